// Round 10
// baseline (18.013 us; speedup 1.0000x reference)
//
#include <hip/hip_runtime.h>

// out = 2 * circconv(d, b),  d = des@K, b = body@K  (circ matvec is commutative)
//
// k1 gemm (UNCHANGED R9): grid 512 (8rt x 32ct x 2kh), block 512; bf16 MFMA
//          32x32 fp32 tile per block into Ppart[kh] (2 x 1 MB).
// k2 conv (REWRITTEN): grid 512 (128 rows x 4 k-quarters), block 256
//          (16 j-groups x 16 threads), 16 outputs/thread via 20-float rolling
//          register window: per 4-j iter = 1 window b128 + 1 bcast + 64 FMA
//          (LDS instrs/thread 96 -> ~34). Swizzle slot^((slot>>2)&7) is
//          conflict-free for stride-1 writes AND stride-4 window reads.

using bf16x8 = __attribute__((ext_vector_type(8))) short;
using f32x4  = __attribute__((ext_vector_type(4))) float;

static __device__ __forceinline__ unsigned cvt_pk_bf16(float lo, float hi) {
    unsigned r;
    asm("v_cvt_pk_bf16_f32 %0, %1, %2" : "=v"(r) : "v"(lo), "v"(hi));
    return r;
}

__global__ __launch_bounds__(512) void gemm_kernel(
    const float* __restrict__ des, const float* __restrict__ body,
    const float* __restrict__ kmat, float* __restrict__ Ppart)
{
    __shared__ float smem[9216];
    short* Bl = (short*)smem;
    float* Rbuf = smem;

    const int tid = threadIdx.x;
    const int bid = blockIdx.x;
    const int kh = bid & 1;
    const int ct = (bid >> 1) & 31;
    const int rt = bid >> 6;
    const int R0 = rt * 32, C0 = ct * 32;
    const int kb = kh * 512;
    const float* Arow = (R0 < 128) ? (des + (size_t)R0 * 1024)
                                   : (body + (size_t)(R0 - 128) * 1024);

    const int lane = tid & 63;
    const int w = tid >> 6;
    const int lr = lane & 15;
    const int lk = lane >> 4;

    f32x4 acc[2][2];
    #pragma unroll
    for (int q = 0; q < 2; ++q)
        #pragma unroll
        for (int g = 0; g < 2; ++g) acc[q][g] = (f32x4){0.f, 0.f, 0.f, 0.f};

    #pragma unroll
    for (int i = 0; i < 4; ++i) {
        int t4 = tid + i * 512;
        int ke2 = t4 >> 3, c4 = t4 & 7;
        int k = ke2 * 2;
        const float* src = kmat + (size_t)(kb + k) * 1024 + C0 + c4 * 4;
        float4 Fa = *(const float4*)src;
        float4 Fb = *(const float4*)(src + 1024);
        const float fa[4] = {Fa.x, Fa.y, Fa.z, Fa.w};
        const float fb[4] = {Fb.x, Fb.y, Fb.z, Fb.w};
        int kg = (k >> 3) & 3, kc = k >> 5, sw = (k >> 3) & 7;
        #pragma unroll
        for (int u = 0; u < 4; ++u) {
            int c = c4 * 4 + u;
            int unit = (((c >> 4) * 16 + kc) << 6) + (kg << 4) + ((c & 15) ^ sw);
            *(unsigned*)&Bl[unit * 8 + (k & 7)] = cvt_pk_bf16(fa[u], fb[u]);
        }
    }
    __syncthreads();

    #pragma unroll
    for (int s = 0; s < 2; ++s) {
        const int kc = w * 2 + s;
        const int kglob = kb + kc * 32 + lk * 8;

        bf16x8 afr[2];
        #pragma unroll
        for (int q = 0; q < 2; ++q) {
            const float* ap = Arow + (size_t)(q * 16 + lr) * 1024 + kglob;
            float4 F0 = *(const float4*)ap;
            float4 F1 = *(const float4*)(ap + 4);
            uint4 ua;
            ua.x = cvt_pk_bf16(F0.x, F0.y);
            ua.y = cvt_pk_bf16(F0.z, F0.w);
            ua.z = cvt_pk_bf16(F1.x, F1.y);
            ua.w = cvt_pk_bf16(F1.z, F1.w);
            afr[q] = *(bf16x8*)&ua;
        }
        const int slot = lr ^ ((kc * 4 + lk) & 7);
        #pragma unroll
        for (int g = 0; g < 2; ++g) {
            int unit = ((g * 16 + kc) << 6) + (lk << 4) + slot;
            bf16x8 bfr = *(const bf16x8*)&Bl[unit * 8];
            acc[0][g] = __builtin_amdgcn_mfma_f32_16x16x32_bf16(bfr, afr[0], acc[0][g], 0, 0, 0);
            acc[1][g] = __builtin_amdgcn_mfma_f32_16x16x32_bf16(bfr, afr[1], acc[1][g], 0, 0, 0);
        }
    }
    __syncthreads();

    #pragma unroll
    for (int q = 0; q < 2; ++q)
        #pragma unroll
        for (int g = 0; g < 2; ++g) {
            int r = q * 16 + lr;
            int c = g * 16 + (lk << 2);
            *(f32x4*)&Rbuf[w * 1152 + r * 36 + c] = acc[q][g];
        }
    __syncthreads();
    {
        int o = tid * 2;
        int r = o >> 5, c = o & 31;
        float2 s = make_float2(0.f, 0.f);
        #pragma unroll
        for (int u = 0; u < 8; ++u) {
            float2 v = *(const float2*)&Rbuf[u * 1152 + r * 36 + c];
            s.x += v.x; s.y += v.y;
        }
        *(float2*)(Ppart + (size_t)kh * 262144 + (size_t)(R0 + r) * 1024 + C0 + c) = s;
    }
}

__global__ __launch_bounds__(256) void conv_kernel(
    const float* __restrict__ Ppart, float* __restrict__ out)
{
    __shared__ float dl[1024];      // swizzled: f4 slot ^ ((slot>>2)&7)
    __shared__ float bl[1024];      // linear (broadcast reads)
    __shared__ float red[4352];     // 256 threads x 17 (pad) = 17 KB

    const int tid = threadIdx.x;
    const int bid = blockIdx.x;
    const int r = bid >> 2;         // row 0..127
    const int kq = bid & 3;         // k-quarter

    // stage: sum the two K-half partials; dl swizzled, bl linear
    {
        const float* Pd0 = Ppart + (size_t)r * 1024;
        const float* Pd1 = Pd0 + 262144;
        const float* Pb0 = Ppart + (size_t)(128 + r) * 1024;
        const float* Pb1 = Pb0 + 262144;
        float4 a = ((const float4*)Pd0)[tid], b = ((const float4*)Pd1)[tid];
        ((float4*)dl)[tid ^ ((tid >> 2) & 7)] =
            make_float4(a.x + b.x, a.y + b.y, a.z + b.z, a.w + b.w);
        float4 e = ((const float4*)Pb0)[tid], f = ((const float4*)Pb1)[tid];
        ((float4*)bl)[tid] =
            make_float4(e.x + f.x, e.y + f.y, e.z + f.z, e.w + f.w);
    }
    __syncthreads();

    const int jg = tid >> 4;        // j-group 0..15 (64 j each)
    const int t  = tid & 15;        // 16 threads x 16 outputs
    const int k0 = (kq * 256 + t * 16 - jg * 64) & 1023;   // mult of 16

#define RD(fidx) (((const float4*)dl)[(((fidx) >> 2) ^ ((((fidx) >> 2) >> 2) & 7))])

    // rolling window c[i] = d[(k0 - jc - 4 + i) & 1023], i = 0..19
    float c[20];
    { float4 v = RD((k0 - 4) & 1023); c[0]=v.x; c[1]=v.y; c[2]=v.z; c[3]=v.w; }
    { float4 v = RD(k0);              c[4]=v.x; c[5]=v.y; c[6]=v.z; c[7]=v.w; }
    { float4 v = RD((k0+4) & 1023);   c[8]=v.x; c[9]=v.y; c[10]=v.z; c[11]=v.w; }
    { float4 v = RD((k0+8) & 1023);   c[12]=v.x; c[13]=v.y; c[14]=v.z; c[15]=v.w; }
    { float4 v = RD((k0+12) & 1023);  c[16]=v.x; c[17]=v.y; c[18]=v.z; c[19]=v.w; }

    float acc[16];
    #pragma unroll
    for (int q = 0; q < 16; ++q) acc[q] = 0.f;

    const float* bq = bl + jg * 64;
    #pragma unroll
    for (int jc = 0; jc < 64; jc += 4) {
        float4 bv4 = *(const float4*)&bq[jc];
        float4 Nv = RD((k0 - jc - 8) & 1023);     // next window chunk
        const float bs[4] = {bv4.x, bv4.y, bv4.z, bv4.w};
        // acc[q] += b[j] * d[k0 + q - (jc+s)];  d-index = c[q + 4 - s]
        #pragma unroll
        for (int s = 0; s < 4; ++s)
            #pragma unroll
            for (int q = 0; q < 16; ++q)
                acc[q] += bs[s] * c[q + 4 - s];
        // roll window down by 4 (pure renames after full unroll)
        #pragma unroll
        for (int i = 19; i >= 4; --i) c[i] = c[i - 4];
        c[0] = Nv.x; c[1] = Nv.y; c[2] = Nv.z; c[3] = Nv.w;
    }
#undef RD

    {
        float* rd = red + tid * 17;
        #pragma unroll
        for (int q = 0; q < 16; ++q) rd[q] = acc[q];
    }
    __syncthreads();
    {
        // output o = tid: produced by (t_src = tid>>4, q = tid&15) over 16 jg
        int base = ((tid >> 4)) * 17 + (tid & 15);
        float s = 0.f;
        #pragma unroll
        for (int u = 0; u < 16; ++u) s += red[u * 272 + base];
        out[(size_t)r * 1024 + kq * 256 + tid] = 2.f * s;
    }
}

extern "C" void kernel_launch(void* const* d_in, const int* in_sizes, int n_in,
                              void* d_out, int out_size, void* d_ws, size_t ws_size,
                              hipStream_t stream) {
    const float* des  = (const float*)d_in[0];
    const float* body = (const float*)d_in[1];
    const float* kmat = (const float*)d_in[2];
    float* Ppart = (float*)d_ws;   // 2 x 256 x 1024 fp32 = 2 MB

    gemm_kernel<<<512, 512, 0, stream>>>(des, body, kmat, Ppart);
    conv_kernel<<<512, 256, 0, stream>>>(Ppart, (float*)d_out);
}

// Round 11
// 17.628 us; speedup vs baseline: 1.0218x; 1.0218x over previous
//
#include <hip/hip_runtime.h>

// out = 2 * circconv(d, b),  d = des@K, b = body@K  (circ matvec is commutative)
//
// Best-measured configuration (R9 = 17.85 us):
// k1 gemm: grid 512 (8 rt x 32 ct x 2 kh), block 512 (8 waves) -> 2 blocks/CU.
//          Each block: one K-half (512 k) of a fp32 32x32 tile of P=[d;b];
//          A global->reg bf16 (v_cvt_pk), B in fragment-linear XOR-swizzled LDS;
//          single stage/sync/MFMA pass; cross-wave padded-LDS reduce;
//          write Ppart[kh] (2 x 1 MB fp32, no atomics).
// k2 conv: grid 256 (128 rows x 2 k-halves), block 512 (8 waves = 8 j-eighths).
//          Staging sums Ppart[0]+Ppart[1]; dl XOR f4-slot swizzled.
//          Rolling float4-window core, 8 outputs/thread; padded-LDS j-reduce.

using bf16x8 = __attribute__((ext_vector_type(8))) short;
using f32x4  = __attribute__((ext_vector_type(4))) float;

static __device__ __forceinline__ unsigned cvt_pk_bf16(float lo, float hi) {
    unsigned r;
    asm("v_cvt_pk_bf16_f32 %0, %1, %2" : "=v"(r) : "v"(lo), "v"(hi));
    return r;
}

__global__ __launch_bounds__(512) void gemm_kernel(
    const float* __restrict__ des, const float* __restrict__ body,
    const float* __restrict__ kmat, float* __restrict__ Ppart)
{
    __shared__ float smem[9216];     // 36 KB: Bl (32 KB) then Rbuf (36 KB)
    short* Bl = (short*)smem;
    float* Rbuf = smem;

    const int tid = threadIdx.x;
    const int bid = blockIdx.x;
    const int kh = bid & 1;            // K-half
    const int ct = (bid >> 1) & 31;    // col band (32 cols)
    const int rt = bid >> 6;           // row band (32 virtual rows)
    const int R0 = rt * 32, C0 = ct * 32;
    const int kb = kh * 512;
    const float* Arow = (R0 < 128) ? (des + (size_t)R0 * 1024)
                                   : (body + (size_t)(R0 - 128) * 1024);

    const int lane = tid & 63;
    const int w = tid >> 6;            // wave 0..7 -> k-chunks {2w, 2w+1}
    const int lr = lane & 15;
    const int lk = lane >> 4;

    f32x4 acc[2][2];
    #pragma unroll
    for (int q = 0; q < 2; ++q)
        #pragma unroll
        for (int g = 0; g < 2; ++g) acc[q][g] = (f32x4){0.f, 0.f, 0.f, 0.f};

    // stage B: 512k x 32c bf16, fragment-linear + XOR slot swizzle (R7-verified)
    #pragma unroll
    for (int i = 0; i < 4; ++i) {
        int t4 = tid + i * 512;
        int ke2 = t4 >> 3, c4 = t4 & 7;
        int k = ke2 * 2;
        const float* src = kmat + (size_t)(kb + k) * 1024 + C0 + c4 * 4;
        float4 Fa = *(const float4*)src;
        float4 Fb = *(const float4*)(src + 1024);
        const float fa[4] = {Fa.x, Fa.y, Fa.z, Fa.w};
        const float fb[4] = {Fb.x, Fb.y, Fb.z, Fb.w};
        int kg = (k >> 3) & 3, kc = k >> 5, sw = (k >> 3) & 7;
        #pragma unroll
        for (int u = 0; u < 4; ++u) {
            int c = c4 * 4 + u;
            int unit = (((c >> 4) * 16 + kc) << 6) + (kg << 4) + ((c & 15) ^ sw);
            *(unsigned*)&Bl[unit * 8 + (k & 7)] = cvt_pk_bf16(fa[u], fb[u]);
        }
    }
    __syncthreads();

    #pragma unroll
    for (int s = 0; s < 2; ++s) {
        const int kc = w * 2 + s;
        const int kglob = kb + kc * 32 + lk * 8;

        bf16x8 afr[2];
        #pragma unroll
        for (int q = 0; q < 2; ++q) {
            const float* ap = Arow + (size_t)(q * 16 + lr) * 1024 + kglob;
            float4 F0 = *(const float4*)ap;
            float4 F1 = *(const float4*)(ap + 4);
            uint4 ua;
            ua.x = cvt_pk_bf16(F0.x, F0.y);
            ua.y = cvt_pk_bf16(F0.z, F0.w);
            ua.z = cvt_pk_bf16(F1.x, F1.y);
            ua.w = cvt_pk_bf16(F1.z, F1.w);
            afr[q] = *(bf16x8*)&ua;
        }
        const int slot = lr ^ ((kc * 4 + lk) & 7);
        #pragma unroll
        for (int g = 0; g < 2; ++g) {
            int unit = ((g * 16 + kc) << 6) + (lk << 4) + slot;
            bf16x8 bfr = *(const bf16x8*)&Bl[unit * 8];
            // swapped operands (R5-verified): lane row = lr, 4 regs = cols
            acc[0][g] = __builtin_amdgcn_mfma_f32_16x16x32_bf16(bfr, afr[0], acc[0][g], 0, 0, 0);
            acc[1][g] = __builtin_amdgcn_mfma_f32_16x16x32_bf16(bfr, afr[1], acc[1][g], 0, 0, 0);
        }
    }
    __syncthreads();

    // cross-wave reduce in padded LDS (aliases Bl)
    #pragma unroll
    for (int q = 0; q < 2; ++q)
        #pragma unroll
        for (int g = 0; g < 2; ++g) {
            int r = q * 16 + lr;
            int c = g * 16 + (lk << 2);
            *(f32x4*)&Rbuf[w * 1152 + r * 36 + c] = acc[q][g];
        }
    __syncthreads();
    {
        int o = tid * 2;
        int r = o >> 5, c = o & 31;
        float2 s = make_float2(0.f, 0.f);
        #pragma unroll
        for (int u = 0; u < 8; ++u) {
            float2 v = *(const float2*)&Rbuf[u * 1152 + r * 36 + c];
            s.x += v.x; s.y += v.y;
        }
        *(float2*)(Ppart + (size_t)kh * 262144 + (size_t)(R0 + r) * 1024 + C0 + c) = s;
    }
}

__global__ __launch_bounds__(512) void conv_kernel(
    const float* __restrict__ Ppart, float* __restrict__ out)
{
    __shared__ float dl[1024];     // XOR f4-slot swizzled
    __shared__ float bl[1024];     // linear (broadcast reads only)
    __shared__ float red[4608];    // 8 jo x 64 t x 9 (pad) = 18 KB

    const int tid = threadIdx.x;
    const int bid = blockIdx.x;
    const int r = bid >> 1;        // row 0..127
    const int h = bid & 1;         // k-half

    // stage: sum the two K-half partials; dl swizzled, bl linear
    {
        int isB = tid >> 8, i4 = tid & 255;
        const float4* s0 = (const float4*)(Ppart + (size_t)(isB ? 128 + r : r) * 1024);
        const float4* s1 = (const float4*)(Ppart + 262144 + (size_t)(isB ? 128 + r : r) * 1024);
        float4 a = s0[i4], b = s1[i4];
        float4 v = make_float4(a.x + b.x, a.y + b.y, a.z + b.z, a.w + b.w);
        if (isB) ((float4*)bl)[i4] = v;
        else     ((float4*)dl)[i4 ^ ((i4 >> 3) & 7)] = v;
    }
    __syncthreads();

    const int jo = tid >> 6;       // wave index = j-eighth (bv stays uniform)
    const int t  = tid & 63;       // k-octet
    const int k0 = (h * 512 + t * 8 - jo * 128) & 1023;   // multiple of 8

#define RD(fidx) (((const float4*)dl)[(((fidx) >> 2) ^ ((((fidx) >> 2) >> 3) & 7))])

    float acc[8] = {0.f, 0.f, 0.f, 0.f, 0.f, 0.f, 0.f, 0.f};
    float4 A  = RD(k0);
    float4 Bv = RD((k0 + 4) & 1023);

    const float* bq = bl + jo * 128;
    #pragma unroll 4
    for (int jc = 0; jc < 128; jc += 4) {
        float4 bv = *(const float4*)&bq[jc];           // wave-uniform broadcast
        float4 Nv = RD((k0 - jc - 4) & 1023);
        acc[0] += bv.x * A.x;  acc[1] += bv.x * A.y;  acc[2] += bv.x * A.z;  acc[3] += bv.x * A.w;
        acc[4] += bv.x * Bv.x; acc[5] += bv.x * Bv.y; acc[6] += bv.x * Bv.z; acc[7] += bv.x * Bv.w;
        acc[0] += bv.y * Nv.w; acc[1] += bv.y * A.x;  acc[2] += bv.y * A.y;  acc[3] += bv.y * A.z;
        acc[4] += bv.y * A.w;  acc[5] += bv.y * Bv.x; acc[6] += bv.y * Bv.y; acc[7] += bv.y * Bv.z;
        acc[0] += bv.z * Nv.z; acc[1] += bv.z * Nv.w; acc[2] += bv.z * A.x;  acc[3] += bv.z * A.y;
        acc[4] += bv.z * A.z;  acc[5] += bv.z * A.w;  acc[6] += bv.z * Bv.x; acc[7] += bv.z * Bv.y;
        acc[0] += bv.w * Nv.y; acc[1] += bv.w * Nv.z; acc[2] += bv.w * Nv.w; acc[3] += bv.w * A.x;
        acc[4] += bv.w * A.y;  acc[5] += bv.w * A.z;  acc[6] += bv.w * A.w;  acc[7] += bv.w * Bv.x;
        Bv = A; A = Nv;
    }
#undef RD

    {
        float* rd = red + jo * 576 + t * 9;
        #pragma unroll
        for (int q = 0; q < 8; ++q) rd[q] = acc[q];
    }
    __syncthreads();
    {
        // output o = tid (one float each; 2 KB contiguous store per block)
        int tt = tid >> 3, qq = tid & 7;
        float s = 0.f;
        #pragma unroll
        for (int u = 0; u < 8; ++u) s += red[u * 576 + tt * 9 + qq];
        out[(size_t)r * 1024 + h * 512 + tid] = 2.f * s;
    }
}

extern "C" void kernel_launch(void* const* d_in, const int* in_sizes, int n_in,
                              void* d_out, int out_size, void* d_ws, size_t ws_size,
                              hipStream_t stream) {
    const float* des  = (const float*)d_in[0];
    const float* body = (const float*)d_in[1];
    const float* kmat = (const float*)d_in[2];
    float* Ppart = (float*)d_ws;   // 2 x 256 x 1024 fp32 = 2 MB

    gemm_kernel<<<512, 512, 0, stream>>>(des, body, kmat, Ppart);
    conv_kernel<<<256, 512, 0, stream>>>(Ppart, (float*)d_out);
}